// Round 9
// baseline (1012.525 us; speedup 1.0000x reference)
//
#include <hip/hip_runtime.h>
#include <cstddef>

#define TT 256
#define HH 128
#define EST 132   // E row stride: b128 reads land 8 dwords on every bank = balanced

__device__ __forceinline__ float rdlane(float v, int l) {
  return __int_as_float(__builtin_amdgcn_readlane(__float_as_int(v), l));
}
__device__ __forceinline__ float fast_sigmoid(float x) {
  const float L2E = 1.4426950408889634f;
  float y = __builtin_amdgcn_exp2f(-x * L2E);
  return __builtin_amdgcn_rcpf(1.0f + y);
}
__device__ __forceinline__ float fast_tanh(float x) {
  const float C2 = 2.8853900817779268f;   // 2*log2(e)
  float y = __builtin_amdgcn_exp2f(x * C2);
  return 1.0f - 2.0f * __builtin_amdgcn_rcpf(1.0f + y);
}

// One workgroup per batch element; 1024 threads = 16 waves (4/SIMD, 1 WG/CU).
// Same 3-barrier skeleton as R8 (R: reduce+gates | S: C+Apre | T: U+D) with
// per-thread register footprint halved so nothing spills at the 128-VGPR cap.
__global__ __launch_bounds__(1024)
void decoder_kernel(const float* __restrict__ x,
                    const float* __restrict__ enc_output,
                    const float* __restrict__ h0,
                    const float* __restrict__ c0,
                    const float* __restrict__ W1,
                    const float* __restrict__ W2,
                    const float* __restrict__ V,
                    const float* __restrict__ Wk,
                    const float* __restrict__ Wr,
                    const float* __restrict__ bias,
                    float* __restrict__ out)
{
  __shared__ float E[TT * EST];      // 135168 B : exp2(C2 * enc_proj)
  __shared__ float zpart[4 * 512];   // 8192 B   : h@Wr k-quarter partials
  __shared__ float part[8 * 128];    // 4096 B   : phase-C partials [jgroup][k]
  __shared__ float scp[8 * 257];     // 8224 B   : phase-D partials [kgroup][t]
  __shared__ float hbuf[HH];         // 512 B
  __shared__ float xloc[TT * 2];     // 2048 B
  __shared__ float v2l[HH];          // 512 B    : -2*V
  // total 158752 B <= 160 KiB

  const int u    = threadIdx.x;
  const int b    = blockIdx.x;
  const int lane = u & 63;
  const int w    = u >> 6;           // wave 0..15
  const float C2  = 2.8853900817779268f;
  const float L2E = 1.4426950408889634f;

  // ---------------- P0: enc_proj = enc_output[b] @ W1 -> E (raw) ----------------
  {
    const float* encb = enc_output + (size_t)b * TT * HH;
    const int tsub = u >> 4;         // 0..63
    const int ks   = (u & 15) * 8;
    for (int p = 0; p < 4; ++p) {
      const int tt = p * 64 + tsub;
      float4 a0 = {0.f, 0.f, 0.f, 0.f};
      float4 a1 = {0.f, 0.f, 0.f, 0.f};
      const float4* er4 = (const float4*)(encb + tt * HH);
      for (int j4 = 0; j4 < 32; ++j4) {
        const float4 ev = er4[j4];
        const float* w1p = W1 + (j4 * 4) * HH + ks;
        float4 wa, wb;
        wa = *(const float4*)(w1p + 0 * HH); wb = *(const float4*)(w1p + 0 * HH + 4);
        a0.x += ev.x * wa.x; a0.y += ev.x * wa.y; a0.z += ev.x * wa.z; a0.w += ev.x * wa.w;
        a1.x += ev.x * wb.x; a1.y += ev.x * wb.y; a1.z += ev.x * wb.z; a1.w += ev.x * wb.w;
        wa = *(const float4*)(w1p + 1 * HH); wb = *(const float4*)(w1p + 1 * HH + 4);
        a0.x += ev.y * wa.x; a0.y += ev.y * wa.y; a0.z += ev.y * wa.z; a0.w += ev.y * wa.w;
        a1.x += ev.y * wb.x; a1.y += ev.y * wb.y; a1.z += ev.y * wb.z; a1.w += ev.y * wb.w;
        wa = *(const float4*)(w1p + 2 * HH); wb = *(const float4*)(w1p + 2 * HH + 4);
        a0.x += ev.z * wa.x; a0.y += ev.z * wa.y; a0.z += ev.z * wa.z; a0.w += ev.z * wa.w;
        a1.x += ev.z * wb.x; a1.y += ev.z * wb.y; a1.z += ev.z * wb.z; a1.w += ev.z * wb.w;
        wa = *(const float4*)(w1p + 3 * HH); wb = *(const float4*)(w1p + 3 * HH + 4);
        a0.x += ev.w * wa.x; a0.y += ev.w * wa.y; a0.z += ev.w * wa.z; a0.w += ev.w * wa.w;
        a1.x += ev.w * wb.x; a1.y += ev.w * wb.y; a1.z += ev.w * wb.z; a1.w += ev.w * wb.w;
      }
      *(float4*)(&E[tt * EST + ks])     = a0;
      *(float4*)(&E[tt * EST + ks + 4]) = a1;
    }
  }
  if (u < 512) xloc[u] = x[b * (TT * 2) + u];
  if (u < HH)  v2l[u]  = -2.0f * V[u];

  // ---------------- persistent registers ----------------
  // Apre: thread (kq = u>>8, cs = u&255) owns cols 2cs,2cs+1; k in [32kq,+32)
  const int kq = u >> 8;
  const int cs = u & 255;
  float2 wr2[32];
  #pragma unroll
  for (int i = 0; i < 32; ++i)
    wr2[i] = *(const float2*)(Wr + (size_t)(32 * kq + i) * 512 + 2 * cs);
  // Gates: thread u<128 owns unit m, all 4 gates
  const int m = u & 127;
  float wkA[4], wkB[4], bbg[4];
  #pragma unroll
  for (int gg = 0; gg < 4; ++gg) {
    wkA[gg] = Wk[gg * HH + m];
    wkB[gg] = Wk[512 + gg * HH + m];
    bbg[gg] = bias[gg * HH + m];
  }
  float c = c0[b * HH + m];
  // Phase C: wave w -> jg = w>>1 (j in [16jg,+16)), kb = w&1 (k = 64kb+lane)
  const int jg = w >> 1;
  const int kb = w & 1;
  float w2col[16];
  #pragma unroll
  for (int jj = 0; jj < 16; ++jj)
    w2col[jj] = W2[(16 * jg + jj) * HH + 64 * kb + lane];
  // Phase D: wave w -> kg = w&7 (k in [16kg,+16)), th = w>>3 (t-half)
  const int kg = w & 7;
  const int th = w >> 3;
  const int kstar = 16 * kg + (lane & 15);
  float ptr0 = 1.0f, ptr1 = 1.0f;
  float svr;
  {
    float v = V[lane] + V[64 + lane];
    #pragma unroll
    for (int o = 1; o < 64; o <<= 1) v += __shfl_xor(v, o, 64);
    svr = v;
  }

  __syncthreads();   // P0 staging + xloc/v2l visible

  // ---------------- P1: E = exp2(C2 * enc_proj) in place (own chunks) ----------
  {
    float* Er = &E[(u >> 2) * EST + 32 * (u & 3)];
    #pragma unroll
    for (int i = 0; i < 8; ++i) {
      float4 ev = *(const float4*)(Er + 4 * i);
      ev.x = __builtin_amdgcn_exp2f(ev.x * C2);
      ev.y = __builtin_amdgcn_exp2f(ev.y * C2);
      ev.z = __builtin_amdgcn_exp2f(ev.z * C2);
      ev.w = __builtin_amdgcn_exp2f(ev.w * C2);
      *(float4*)(Er + 4 * i) = ev;
    }
  }
  // prologue Apre: zpart = h0 @ Wr (h0 from global; hbuf untouched -> no race)
  {
    float hA0 = h0[(size_t)b * HH + 32 * kq + (lane & 31)];
    float zx = 0.0f, zy = 0.0f;
    #pragma unroll
    for (int i = 0; i < 32; ++i) {
      float hi = rdlane(hA0, i);
      zx += hi * wr2[i].x;
      zy += hi * wr2[i].y;
    }
    zpart[kq * 512 + 2 * cs + 0] = zx;
    zpart[kq * 512 + 2 * cs + 1] = zy;
  }
  __syncthreads();   // E final + zpart(h0) visible

  float* outb = out + (size_t)b * TT * TT;

  // ---------------- step loop: 3 barriers ----------------
  #pragma unroll 1
  for (int step = 0; step < TT; ++step) {
    // ==== R window: reduce scores(step-1) + ptr + gates -> h_step ====
    if (step > 0 && w < 4) {
      float s0 = 0.f, s1 = 0.f, s2 = 0.f, s3 = 0.f;
      #pragma unroll
      for (int q = 0; q < 8; ++q) {
        s0 += scp[q * 257 + 0 * 64 + lane];
        s1 += scp[q * 257 + 1 * 64 + lane];
        s2 += scp[q * 257 + 2 * 64 + lane];
        s3 += scp[q * 257 + 3 * 64 + lane];
      }
      s0 += svr; s1 += svr; s2 += svr; s3 += svr;
      float p0 = __builtin_amdgcn_exp2f((s0 - 12.0f) * L2E);
      float p1 = __builtin_amdgcn_exp2f((s1 - 12.0f) * L2E);
      float p2 = __builtin_amdgcn_exp2f((s2 - 12.0f) * L2E);
      float p3 = __builtin_amdgcn_exp2f((s3 - 12.0f) * L2E);
      float m4 = fmaxf(fmaxf(s0, s1), fmaxf(s2, s3));
      int ttl = (s0 == m4) ? 0 : (s1 == m4) ? 1 : (s2 == m4) ? 2 : 3;
      float ws4 = (p0 + p1) + (p2 + p3);
      float mx = m4;
      #pragma unroll
      for (int o = 1; o < 64; o <<= 1) {
        mx  = fmaxf(mx, __shfl_xor(mx, o));
        ws4 += __shfl_xor(ws4, o);
      }
      unsigned long long bal = __ballot(m4 == mx);
      int ls  = __ffsll((unsigned long long)bal) - 1;
      int tts = __builtin_amdgcn_readlane(ttl, ls);
      int fbt = 64 * tts + ls;
      ptr0 = xloc[2 * fbt + 0];
      ptr1 = xloc[2 * fbt + 1];
      float pw = (w == 0) ? p0 : (w == 1) ? p1 : (w == 2) ? p2 : p3;
      outb[(size_t)(step - 1) * TT + 64 * w + lane] = pw * __builtin_amdgcn_rcpf(ws4);
    }
    if (u < HH) {   // gates: unit m, all 4 gates in-thread
      float z0 = bbg[0] + ptr0 * wkA[0] + ptr1 * wkB[0];
      float z1 = bbg[1] + ptr0 * wkA[1] + ptr1 * wkB[1];
      float z2 = bbg[2] + ptr0 * wkA[2] + ptr1 * wkB[2];
      float z3 = bbg[3] + ptr0 * wkA[3] + ptr1 * wkB[3];
      #pragma unroll
      for (int q = 0; q < 4; ++q) {
        z0 += zpart[q * 512 + 0 * HH + m];
        z1 += zpart[q * 512 + 1 * HH + m];
        z2 += zpart[q * 512 + 2 * HH + m];
        z3 += zpart[q * 512 + 3 * HH + m];
      }
      float ig = fast_sigmoid(z0);
      float fg = fast_sigmoid(z1);
      float gg = fast_tanh(z2);
      float og = fast_sigmoid(z3);
      c = fg * c + ig * gg;
      hbuf[m] = og * fast_tanh(c);
    }
    __syncthreads();                 // (W1) h_step visible

    // ==== S window: C (u_k partials) + Apre (h_step @ Wr) ====
    float hC = hbuf[16 * jg + (lane & 15)];
    float hA = hbuf[32 * kq + (lane & 31)];
    {
      float cp0 = 0.0f, cp1 = 0.0f;
      #pragma unroll
      for (int jj = 0; jj < 16; jj += 2) {
        cp0 += rdlane(hC, jj)     * w2col[jj];
        cp1 += rdlane(hC, jj + 1) * w2col[jj + 1];
      }
      part[jg * 128 + 64 * kb + lane] = cp0 + cp1;
    }
    {
      float zx = 0.0f, zy = 0.0f;
      #pragma unroll
      for (int i = 0; i < 32; ++i) {
        float hi = rdlane(hA, i);
        zx += hi * wr2[i].x;
        zy += hi * wr2[i].y;
      }
      zpart[kq * 512 + 2 * cs + 0] = zx;
      zpart[kq * 512 + 2 * cs + 1] = zy;
    }
    __syncthreads();                 // (W2) part + zpart visible

    // ==== T window: U + D (pair-merged rcp, two half-k passes) -> scp ====
    float Uk;
    {
      float usum = ((part[0 * 128 + kstar] + part[1 * 128 + kstar]) +
                    (part[2 * 128 + kstar] + part[3 * 128 + kstar])) +
                   ((part[4 * 128 + kstar] + part[5 * 128 + kstar]) +
                    (part[6 * 128 + kstar] + part[7 * 128 + kstar]));
      Uk = __builtin_amdgcn_exp2f(usum * C2);
    }
    {
      const int t0r = 128 * th + lane;
      const int t1r = 128 * th + 64 + lane;
      float accA = 0.0f, accB = 0.0f;
      #pragma unroll
      for (int hf = 0; hf < 2; ++hf) {
        float u0 = rdlane(Uk, 8 * hf + 0);
        float u1 = rdlane(Uk, 8 * hf + 1);
        float u2 = rdlane(Uk, 8 * hf + 2);
        float u3 = rdlane(Uk, 8 * hf + 3);
        float u4 = rdlane(Uk, 8 * hf + 4);
        float u5 = rdlane(Uk, 8 * hf + 5);
        float u6 = rdlane(Uk, 8 * hf + 6);
        float u7 = rdlane(Uk, 8 * hf + 7);
        float4 va = *(const float4*)(v2l + 16 * kg + 8 * hf);
        float4 vb = *(const float4*)(v2l + 16 * kg + 8 * hf + 4);
        float t0, t1, n;
        {
          const float* Er = &E[t0r * EST + 16 * kg + 8 * hf];
          float4 e0 = *(const float4*)(Er);
          float4 e1 = *(const float4*)(Er + 4);
          t0 = fmaf(e0.x, u0, 1.0f); t1 = fmaf(e0.y, u1, 1.0f);
          n  = fmaf(va.y, t0, va.x * t1);
          accA = fmaf(n, __builtin_amdgcn_rcpf(t0 * t1), accA);
          t0 = fmaf(e0.z, u2, 1.0f); t1 = fmaf(e0.w, u3, 1.0f);
          n  = fmaf(va.w, t0, va.z * t1);
          accA = fmaf(n, __builtin_amdgcn_rcpf(t0 * t1), accA);
          t0 = fmaf(e1.x, u4, 1.0f); t1 = fmaf(e1.y, u5, 1.0f);
          n  = fmaf(vb.y, t0, vb.x * t1);
          accA = fmaf(n, __builtin_amdgcn_rcpf(t0 * t1), accA);
          t0 = fmaf(e1.z, u6, 1.0f); t1 = fmaf(e1.w, u7, 1.0f);
          n  = fmaf(vb.w, t0, vb.z * t1);
          accA = fmaf(n, __builtin_amdgcn_rcpf(t0 * t1), accA);
        }
        {
          const float* Er = &E[t1r * EST + 16 * kg + 8 * hf];
          float4 e0 = *(const float4*)(Er);
          float4 e1 = *(const float4*)(Er + 4);
          t0 = fmaf(e0.x, u0, 1.0f); t1 = fmaf(e0.y, u1, 1.0f);
          n  = fmaf(va.y, t0, va.x * t1);
          accB = fmaf(n, __builtin_amdgcn_rcpf(t0 * t1), accB);
          t0 = fmaf(e0.z, u2, 1.0f); t1 = fmaf(e0.w, u3, 1.0f);
          n  = fmaf(va.w, t0, va.z * t1);
          accB = fmaf(n, __builtin_amdgcn_rcpf(t0 * t1), accB);
          t0 = fmaf(e1.x, u4, 1.0f); t1 = fmaf(e1.y, u5, 1.0f);
          n  = fmaf(vb.y, t0, vb.x * t1);
          accB = fmaf(n, __builtin_amdgcn_rcpf(t0 * t1), accB);
          t0 = fmaf(e1.z, u6, 1.0f); t1 = fmaf(e1.w, u7, 1.0f);
          n  = fmaf(vb.w, t0, vb.z * t1);
          accB = fmaf(n, __builtin_amdgcn_rcpf(t0 * t1), accB);
        }
      }
      scp[kg * 257 + t0r] = accA;
      scp[kg * 257 + t1r] = accB;
    }
    __syncthreads();                 // (W3) scp visible
  }

  // ---------------- peel: reduce + store final row (step 255) ----------------
  if (w < 4) {
    float s0 = 0.f, s1 = 0.f, s2 = 0.f, s3 = 0.f;
    #pragma unroll
    for (int q = 0; q < 8; ++q) {
      s0 += scp[q * 257 + 0 * 64 + lane];
      s1 += scp[q * 257 + 1 * 64 + lane];
      s2 += scp[q * 257 + 2 * 64 + lane];
      s3 += scp[q * 257 + 3 * 64 + lane];
    }
    s0 += svr; s1 += svr; s2 += svr; s3 += svr;
    float p0 = __builtin_amdgcn_exp2f((s0 - 12.0f) * L2E);
    float p1 = __builtin_amdgcn_exp2f((s1 - 12.0f) * L2E);
    float p2 = __builtin_amdgcn_exp2f((s2 - 12.0f) * L2E);
    float p3 = __builtin_amdgcn_exp2f((s3 - 12.0f) * L2E);
    float ws4 = (p0 + p1) + (p2 + p3);
    #pragma unroll
    for (int o = 1; o < 64; o <<= 1) ws4 += __shfl_xor(ws4, o);
    float pw = (w == 0) ? p0 : (w == 1) ? p1 : (w == 2) ? p2 : p3;
    outb[(size_t)255 * TT + 64 * w + lane] = pw * __builtin_amdgcn_rcpf(ws4);
  }
}

extern "C" void kernel_launch(void* const* d_in, const int* in_sizes, int n_in,
                              void* d_out, int out_size, void* d_ws, size_t ws_size,
                              hipStream_t stream) {
  (void)in_sizes; (void)n_in; (void)d_ws; (void)ws_size; (void)out_size;
  const float* x    = (const float*)d_in[0];
  const float* enc  = (const float*)d_in[1];
  const float* h0   = (const float*)d_in[2];
  const float* c0   = (const float*)d_in[3];
  const float* W1   = (const float*)d_in[4];
  const float* W2   = (const float*)d_in[5];
  const float* V    = (const float*)d_in[6];
  const float* Wk   = (const float*)d_in[7];
  const float* Wr   = (const float*)d_in[8];
  const float* bias = (const float*)d_in[9];
  float* out = (float*)d_out;

  decoder_kernel<<<64, 1024, 0, stream>>>(x, enc, h0, c0, W1, W2, V, Wk, Wr, bias, out);
}

// Round 10
// 1004.819 us; speedup vs baseline: 1.0077x; 1.0077x over previous
//
#include <hip/hip_runtime.h>
#include <cstddef>

#define TT 256
#define HH 128
#define EST 132   // E row stride: b128 reads land 8 dwords on every bank = balanced

__device__ __forceinline__ float rdlane(float v, int l) {
  return __int_as_float(__builtin_amdgcn_readlane(__float_as_int(v), l));
}
__device__ __forceinline__ float fast_sigmoid(float x) {
  const float L2E = 1.4426950408889634f;
  float y = __builtin_amdgcn_exp2f(-x * L2E);
  return __builtin_amdgcn_rcpf(1.0f + y);
}
__device__ __forceinline__ float fast_tanh(float x) {
  const float C2 = 2.8853900817779268f;   // 2*log2(e)
  float y = __builtin_amdgcn_exp2f(x * C2);
  return 1.0f - 2.0f * __builtin_amdgcn_rcpf(1.0f + y);
}

// One workgroup per batch element; 1024 threads = 16 waves (4/SIMD, 1 WG/CU).
// 3-barrier skeleton (R: reduce+gates | S: C+Apre | T: U+D).
// __launch_bounds__(1024, 4): min 4 waves/EU -> 128-VGPR bin. R9's bare
// (1024) made the allocator pick the 64-VGPR bin (8 waves/EU target) and
// spill the ~120-reg working set to AGPR/scratch (WRITE_SIZE +4.3 MB).
__global__ __launch_bounds__(1024, 4)
void decoder_kernel(const float* __restrict__ x,
                    const float* __restrict__ enc_output,
                    const float* __restrict__ h0,
                    const float* __restrict__ c0,
                    const float* __restrict__ W1,
                    const float* __restrict__ W2,
                    const float* __restrict__ V,
                    const float* __restrict__ Wk,
                    const float* __restrict__ Wr,
                    const float* __restrict__ bias,
                    float* __restrict__ out)
{
  __shared__ float E[TT * EST];      // 135168 B : exp2(C2 * enc_proj)
  __shared__ float zpart[4 * 512];   // 8192 B   : h@Wr k-quarter partials
  __shared__ float part[8 * 128];    // 4096 B   : phase-C partials [jgroup][k]
  __shared__ float scp[8 * 257];     // 8224 B   : phase-D partials [kgroup][t]
  __shared__ float hbuf[HH];         // 512 B
  __shared__ float xloc[TT * 2];     // 2048 B
  __shared__ float v2l[HH];          // 512 B    : -2*V
  // total 158752 B <= 160 KiB

  const int u    = threadIdx.x;
  const int b    = blockIdx.x;
  const int lane = u & 63;
  const int w    = u >> 6;           // wave 0..15
  const float C2  = 2.8853900817779268f;
  const float L2E = 1.4426950408889634f;

  // ---------------- P0: enc_proj = enc_output[b] @ W1 -> E (raw) ----------------
  {
    const float* encb = enc_output + (size_t)b * TT * HH;
    const int tsub = u >> 4;         // 0..63
    const int ks   = (u & 15) * 8;
    for (int p = 0; p < 4; ++p) {
      const int tt = p * 64 + tsub;
      float4 a0 = {0.f, 0.f, 0.f, 0.f};
      float4 a1 = {0.f, 0.f, 0.f, 0.f};
      const float4* er4 = (const float4*)(encb + tt * HH);
      for (int j4 = 0; j4 < 32; ++j4) {
        const float4 ev = er4[j4];
        const float* w1p = W1 + (j4 * 4) * HH + ks;
        float4 wa, wb;
        wa = *(const float4*)(w1p + 0 * HH); wb = *(const float4*)(w1p + 0 * HH + 4);
        a0.x += ev.x * wa.x; a0.y += ev.x * wa.y; a0.z += ev.x * wa.z; a0.w += ev.x * wa.w;
        a1.x += ev.x * wb.x; a1.y += ev.x * wb.y; a1.z += ev.x * wb.z; a1.w += ev.x * wb.w;
        wa = *(const float4*)(w1p + 1 * HH); wb = *(const float4*)(w1p + 1 * HH + 4);
        a0.x += ev.y * wa.x; a0.y += ev.y * wa.y; a0.z += ev.y * wa.z; a0.w += ev.y * wa.w;
        a1.x += ev.y * wb.x; a1.y += ev.y * wb.y; a1.z += ev.y * wb.z; a1.w += ev.y * wb.w;
        wa = *(const float4*)(w1p + 2 * HH); wb = *(const float4*)(w1p + 2 * HH + 4);
        a0.x += ev.z * wa.x; a0.y += ev.z * wa.y; a0.z += ev.z * wa.z; a0.w += ev.z * wa.w;
        a1.x += ev.z * wb.x; a1.y += ev.z * wb.y; a1.z += ev.z * wb.z; a1.w += ev.z * wb.w;
        wa = *(const float4*)(w1p + 3 * HH); wb = *(const float4*)(w1p + 3 * HH + 4);
        a0.x += ev.w * wa.x; a0.y += ev.w * wa.y; a0.z += ev.w * wa.z; a0.w += ev.w * wa.w;
        a1.x += ev.w * wb.x; a1.y += ev.w * wb.y; a1.z += ev.w * wb.z; a1.w += ev.w * wb.w;
      }
      *(float4*)(&E[tt * EST + ks])     = a0;
      *(float4*)(&E[tt * EST + ks + 4]) = a1;
    }
  }
  if (u < 512) xloc[u] = x[b * (TT * 2) + u];
  if (u < HH)  v2l[u]  = -2.0f * V[u];

  // ---------------- persistent registers ----------------
  // Apre: thread (kq = u>>8, cs = u&255) owns cols 2cs,2cs+1; k in [32kq,+32)
  const int kq = u >> 8;
  const int cs = u & 255;
  float2 wr2[32];
  #pragma unroll
  for (int i = 0; i < 32; ++i)
    wr2[i] = *(const float2*)(Wr + (size_t)(32 * kq + i) * 512 + 2 * cs);
  // Gates: thread u<128 owns unit m, all 4 gates
  const int m = u & 127;
  float wkA[4], wkB[4], bbg[4];
  #pragma unroll
  for (int gg = 0; gg < 4; ++gg) {
    wkA[gg] = Wk[gg * HH + m];
    wkB[gg] = Wk[512 + gg * HH + m];
    bbg[gg] = bias[gg * HH + m];
  }
  float c = c0[b * HH + m];
  // Phase C: wave w -> jg = w>>1 (j in [16jg,+16)), kb = w&1 (k = 64kb+lane)
  const int jg = w >> 1;
  const int kb = w & 1;
  float w2col[16];
  #pragma unroll
  for (int jj = 0; jj < 16; ++jj)
    w2col[jj] = W2[(16 * jg + jj) * HH + 64 * kb + lane];
  // Phase D: wave w -> kg = w&7 (k in [16kg,+16)), th = w>>3 (t-half)
  const int kg = w & 7;
  const int th = w >> 3;
  const int kstar = 16 * kg + (lane & 15);
  float ptr0 = 1.0f, ptr1 = 1.0f;
  float svr;
  {
    float v = V[lane] + V[64 + lane];
    #pragma unroll
    for (int o = 1; o < 64; o <<= 1) v += __shfl_xor(v, o, 64);
    svr = v;
  }

  __syncthreads();   // P0 staging + xloc/v2l visible

  // ---------------- P1: E = exp2(C2 * enc_proj) in place (own chunks) ----------
  {
    float* Er = &E[(u >> 2) * EST + 32 * (u & 3)];
    #pragma unroll
    for (int i = 0; i < 8; ++i) {
      float4 ev = *(const float4*)(Er + 4 * i);
      ev.x = __builtin_amdgcn_exp2f(ev.x * C2);
      ev.y = __builtin_amdgcn_exp2f(ev.y * C2);
      ev.z = __builtin_amdgcn_exp2f(ev.z * C2);
      ev.w = __builtin_amdgcn_exp2f(ev.w * C2);
      *(float4*)(Er + 4 * i) = ev;
    }
  }
  // prologue Apre: zpart = h0 @ Wr (h0 from global; hbuf untouched -> no race)
  {
    float hA0 = h0[(size_t)b * HH + 32 * kq + (lane & 31)];
    float zx = 0.0f, zy = 0.0f;
    #pragma unroll
    for (int i = 0; i < 32; ++i) {
      float hi = rdlane(hA0, i);
      zx += hi * wr2[i].x;
      zy += hi * wr2[i].y;
    }
    zpart[kq * 512 + 2 * cs + 0] = zx;
    zpart[kq * 512 + 2 * cs + 1] = zy;
  }
  __syncthreads();   // E final + zpart(h0) visible

  float* outb = out + (size_t)b * TT * TT;

  // ---------------- step loop: 3 barriers ----------------
  #pragma unroll 1
  for (int step = 0; step < TT; ++step) {
    // ==== R window: reduce scores(step-1) + ptr + gates -> h_step ====
    if (step > 0 && w < 4) {
      float s0 = 0.f, s1 = 0.f, s2 = 0.f, s3 = 0.f;
      #pragma unroll
      for (int q = 0; q < 8; ++q) {
        s0 += scp[q * 257 + 0 * 64 + lane];
        s1 += scp[q * 257 + 1 * 64 + lane];
        s2 += scp[q * 257 + 2 * 64 + lane];
        s3 += scp[q * 257 + 3 * 64 + lane];
      }
      s0 += svr; s1 += svr; s2 += svr; s3 += svr;
      float p0 = __builtin_amdgcn_exp2f((s0 - 12.0f) * L2E);
      float p1 = __builtin_amdgcn_exp2f((s1 - 12.0f) * L2E);
      float p2 = __builtin_amdgcn_exp2f((s2 - 12.0f) * L2E);
      float p3 = __builtin_amdgcn_exp2f((s3 - 12.0f) * L2E);
      float m4 = fmaxf(fmaxf(s0, s1), fmaxf(s2, s3));
      int ttl = (s0 == m4) ? 0 : (s1 == m4) ? 1 : (s2 == m4) ? 2 : 3;
      float ws4 = (p0 + p1) + (p2 + p3);
      float mx = m4;
      #pragma unroll
      for (int o = 1; o < 64; o <<= 1) {
        mx  = fmaxf(mx, __shfl_xor(mx, o));
        ws4 += __shfl_xor(ws4, o);
      }
      unsigned long long bal = __ballot(m4 == mx);
      int ls  = __ffsll((unsigned long long)bal) - 1;
      int tts = __builtin_amdgcn_readlane(ttl, ls);
      int fbt = 64 * tts + ls;
      ptr0 = xloc[2 * fbt + 0];
      ptr1 = xloc[2 * fbt + 1];
      float pw = (w == 0) ? p0 : (w == 1) ? p1 : (w == 2) ? p2 : p3;
      outb[(size_t)(step - 1) * TT + 64 * w + lane] = pw * __builtin_amdgcn_rcpf(ws4);
    }
    if (u < HH) {   // gates: unit m, all 4 gates in-thread
      float z0 = bbg[0] + ptr0 * wkA[0] + ptr1 * wkB[0];
      float z1 = bbg[1] + ptr0 * wkA[1] + ptr1 * wkB[1];
      float z2 = bbg[2] + ptr0 * wkA[2] + ptr1 * wkB[2];
      float z3 = bbg[3] + ptr0 * wkA[3] + ptr1 * wkB[3];
      #pragma unroll
      for (int q = 0; q < 4; ++q) {
        z0 += zpart[q * 512 + 0 * HH + m];
        z1 += zpart[q * 512 + 1 * HH + m];
        z2 += zpart[q * 512 + 2 * HH + m];
        z3 += zpart[q * 512 + 3 * HH + m];
      }
      float ig = fast_sigmoid(z0);
      float fg = fast_sigmoid(z1);
      float gg = fast_tanh(z2);
      float og = fast_sigmoid(z3);
      c = fg * c + ig * gg;
      hbuf[m] = og * fast_tanh(c);
    }
    __syncthreads();                 // (W1) h_step visible

    // ==== S window: C (u_k partials) + Apre (h_step @ Wr) ====
    float hC = hbuf[16 * jg + (lane & 15)];
    float hA = hbuf[32 * kq + (lane & 31)];
    {
      float cp0 = 0.0f, cp1 = 0.0f;
      #pragma unroll
      for (int jj = 0; jj < 16; jj += 2) {
        cp0 += rdlane(hC, jj)     * w2col[jj];
        cp1 += rdlane(hC, jj + 1) * w2col[jj + 1];
      }
      part[jg * 128 + 64 * kb + lane] = cp0 + cp1;
    }
    {
      float zx = 0.0f, zy = 0.0f;
      #pragma unroll
      for (int i = 0; i < 32; ++i) {
        float hi = rdlane(hA, i);
        zx += hi * wr2[i].x;
        zy += hi * wr2[i].y;
      }
      zpart[kq * 512 + 2 * cs + 0] = zx;
      zpart[kq * 512 + 2 * cs + 1] = zy;
    }
    __syncthreads();                 // (W2) part + zpart visible

    // ==== T window: U + D (pair-merged rcp, two half-k passes) -> scp ====
    float Uk;
    {
      float usum = ((part[0 * 128 + kstar] + part[1 * 128 + kstar]) +
                    (part[2 * 128 + kstar] + part[3 * 128 + kstar])) +
                   ((part[4 * 128 + kstar] + part[5 * 128 + kstar]) +
                    (part[6 * 128 + kstar] + part[7 * 128 + kstar]));
      Uk = __builtin_amdgcn_exp2f(usum * C2);
    }
    {
      const int t0r = 128 * th + lane;
      const int t1r = 128 * th + 64 + lane;
      float accA = 0.0f, accB = 0.0f;
      #pragma unroll
      for (int hf = 0; hf < 2; ++hf) {
        float u0 = rdlane(Uk, 8 * hf + 0);
        float u1 = rdlane(Uk, 8 * hf + 1);
        float u2 = rdlane(Uk, 8 * hf + 2);
        float u3 = rdlane(Uk, 8 * hf + 3);
        float u4 = rdlane(Uk, 8 * hf + 4);
        float u5 = rdlane(Uk, 8 * hf + 5);
        float u6 = rdlane(Uk, 8 * hf + 6);
        float u7 = rdlane(Uk, 8 * hf + 7);
        float4 va = *(const float4*)(v2l + 16 * kg + 8 * hf);
        float4 vb = *(const float4*)(v2l + 16 * kg + 8 * hf + 4);
        float t0, t1, n;
        {
          const float* Er = &E[t0r * EST + 16 * kg + 8 * hf];
          float4 e0 = *(const float4*)(Er);
          float4 e1 = *(const float4*)(Er + 4);
          t0 = fmaf(e0.x, u0, 1.0f); t1 = fmaf(e0.y, u1, 1.0f);
          n  = fmaf(va.y, t0, va.x * t1);
          accA = fmaf(n, __builtin_amdgcn_rcpf(t0 * t1), accA);
          t0 = fmaf(e0.z, u2, 1.0f); t1 = fmaf(e0.w, u3, 1.0f);
          n  = fmaf(va.w, t0, va.z * t1);
          accA = fmaf(n, __builtin_amdgcn_rcpf(t0 * t1), accA);
          t0 = fmaf(e1.x, u4, 1.0f); t1 = fmaf(e1.y, u5, 1.0f);
          n  = fmaf(vb.y, t0, vb.x * t1);
          accA = fmaf(n, __builtin_amdgcn_rcpf(t0 * t1), accA);
          t0 = fmaf(e1.z, u6, 1.0f); t1 = fmaf(e1.w, u7, 1.0f);
          n  = fmaf(vb.w, t0, vb.z * t1);
          accA = fmaf(n, __builtin_amdgcn_rcpf(t0 * t1), accA);
        }
        {
          const float* Er = &E[t1r * EST + 16 * kg + 8 * hf];
          float4 e0 = *(const float4*)(Er);
          float4 e1 = *(const float4*)(Er + 4);
          t0 = fmaf(e0.x, u0, 1.0f); t1 = fmaf(e0.y, u1, 1.0f);
          n  = fmaf(va.y, t0, va.x * t1);
          accB = fmaf(n, __builtin_amdgcn_rcpf(t0 * t1), accB);
          t0 = fmaf(e0.z, u2, 1.0f); t1 = fmaf(e0.w, u3, 1.0f);
          n  = fmaf(va.w, t0, va.z * t1);
          accB = fmaf(n, __builtin_amdgcn_rcpf(t0 * t1), accB);
          t0 = fmaf(e1.x, u4, 1.0f); t1 = fmaf(e1.y, u5, 1.0f);
          n  = fmaf(vb.y, t0, vb.x * t1);
          accB = fmaf(n, __builtin_amdgcn_rcpf(t0 * t1), accB);
          t0 = fmaf(e1.z, u6, 1.0f); t1 = fmaf(e1.w, u7, 1.0f);
          n  = fmaf(vb.w, t0, vb.z * t1);
          accB = fmaf(n, __builtin_amdgcn_rcpf(t0 * t1), accB);
        }
      }
      scp[kg * 257 + t0r] = accA;
      scp[kg * 257 + t1r] = accB;
    }
    __syncthreads();                 // (W3) scp visible
  }

  // ---------------- peel: reduce + store final row (step 255) ----------------
  if (w < 4) {
    float s0 = 0.f, s1 = 0.f, s2 = 0.f, s3 = 0.f;
    #pragma unroll
    for (int q = 0; q < 8; ++q) {
      s0 += scp[q * 257 + 0 * 64 + lane];
      s1 += scp[q * 257 + 1 * 64 + lane];
      s2 += scp[q * 257 + 2 * 64 + lane];
      s3 += scp[q * 257 + 3 * 64 + lane];
    }
    s0 += svr; s1 += svr; s2 += svr; s3 += svr;
    float p0 = __builtin_amdgcn_exp2f((s0 - 12.0f) * L2E);
    float p1 = __builtin_amdgcn_exp2f((s1 - 12.0f) * L2E);
    float p2 = __builtin_amdgcn_exp2f((s2 - 12.0f) * L2E);
    float p3 = __builtin_amdgcn_exp2f((s3 - 12.0f) * L2E);
    float ws4 = (p0 + p1) + (p2 + p3);
    #pragma unroll
    for (int o = 1; o < 64; o <<= 1) ws4 += __shfl_xor(ws4, o);
    float pw = (w == 0) ? p0 : (w == 1) ? p1 : (w == 2) ? p2 : p3;
    outb[(size_t)255 * TT + 64 * w + lane] = pw * __builtin_amdgcn_rcpf(ws4);
  }
}

extern "C" void kernel_launch(void* const* d_in, const int* in_sizes, int n_in,
                              void* d_out, int out_size, void* d_ws, size_t ws_size,
                              hipStream_t stream) {
  (void)in_sizes; (void)n_in; (void)d_ws; (void)ws_size; (void)out_size;
  const float* x    = (const float*)d_in[0];
  const float* enc  = (const float*)d_in[1];
  const float* h0   = (const float*)d_in[2];
  const float* c0   = (const float*)d_in[3];
  const float* W1   = (const float*)d_in[4];
  const float* W2   = (const float*)d_in[5];
  const float* V    = (const float*)d_in[6];
  const float* Wk   = (const float*)d_in[7];
  const float* Wr   = (const float*)d_in[8];
  const float* bias = (const float*)d_in[9];
  float* out = (float*)d_out;

  decoder_kernel<<<64, 1024, 0, stream>>>(x, enc, h0, c0, W1, W2, V, Wk, Wr, bias, out);
}

// Round 11
// 833.188 us; speedup vs baseline: 1.2152x; 1.2060x over previous
//
#include <hip/hip_runtime.h>
#include <cstddef>

#define TT 256
#define HH 128
#define EST 132    // E row stride: b128 reads land 8 dwords on every bank = balanced
#define SCPS 260   // scp row stride: 260*4 % 16 == 0 (b128-aligned rows), banks balanced

__device__ __forceinline__ float rdlane(float v, int l) {
  return __int_as_float(__builtin_amdgcn_readlane(__float_as_int(v), l));
}
__device__ __forceinline__ float fast_sigmoid(float x) {
  const float L2E = 1.4426950408889634f;
  float y = __builtin_amdgcn_exp2f(-x * L2E);
  return __builtin_amdgcn_rcpf(1.0f + y);
}
__device__ __forceinline__ float fast_tanh(float x) {
  const float C2 = 2.8853900817779268f;   // 2*log2(e)
  float y = __builtin_amdgcn_exp2f(x * C2);
  return 1.0f - 2.0f * __builtin_amdgcn_rcpf(1.0f + y);
}

// One workgroup per batch element; 512 threads = 8 waves (2/SIMD).
// TWO barriers/step:  R(reduce+ptr+gates) -> W1 -> [C(wave-local)+U+D+Apre] -> W3.
// Phase C is wave-local (each wave finishes u_k for its own 16 k's via
// shfl_xor(16/32)), removing R8's W2 barrier. Gates spread over all 4 SIMDs.
__global__ __launch_bounds__(512, 2)
void decoder_kernel(const float* __restrict__ x,
                    const float* __restrict__ enc_output,
                    const float* __restrict__ h0,
                    const float* __restrict__ c0,
                    const float* __restrict__ W1,
                    const float* __restrict__ W2,
                    const float* __restrict__ V,
                    const float* __restrict__ Wk,
                    const float* __restrict__ Wr,
                    const float* __restrict__ bias,
                    float* __restrict__ out)
{
  __shared__ float E[TT * EST];      // 135168 B : exp2(C2 * enc_proj)
  __shared__ float zpart[4 * 512];   // 8192 B   : h@Wr k-quarter partials
  __shared__ float scp[8 * SCPS];    // 8320 B   : phase-D partials [kgroup][t]
  __shared__ float hbuf[HH];         // 512 B
  __shared__ float xloc[TT * 2];     // 2048 B
  // total 154240 B <= 160 KiB

  const int u    = threadIdx.x;
  const int b    = blockIdx.x;
  const int lane = u & 63;
  const int w    = u >> 6;           // wave 0..7 (owns k in [16w,16w+16) for C/D)
  const float C2  = 2.8853900817779268f;
  const float L2E = 1.4426950408889634f;

  // ---------------- P0: enc_proj = enc_output[b] @ W1 -> E (raw) ----------------
  {
    const float* encb = enc_output + (size_t)b * TT * HH;
    const int tsub = u >> 4;
    const int ks   = (u & 15) * 8;
    for (int p = 0; p < 8; ++p) {
      const int tt = p * 32 + tsub;
      float4 a0 = {0.f, 0.f, 0.f, 0.f};
      float4 a1 = {0.f, 0.f, 0.f, 0.f};
      const float4* er4 = (const float4*)(encb + tt * HH);
      for (int j4 = 0; j4 < 32; ++j4) {
        const float4 ev = er4[j4];
        const float* w1p = W1 + (j4 * 4) * HH + ks;
        float4 wa, wb;
        wa = *(const float4*)(w1p + 0 * HH); wb = *(const float4*)(w1p + 0 * HH + 4);
        a0.x += ev.x * wa.x; a0.y += ev.x * wa.y; a0.z += ev.x * wa.z; a0.w += ev.x * wa.w;
        a1.x += ev.x * wb.x; a1.y += ev.x * wb.y; a1.z += ev.x * wb.z; a1.w += ev.x * wb.w;
        wa = *(const float4*)(w1p + 1 * HH); wb = *(const float4*)(w1p + 1 * HH + 4);
        a0.x += ev.y * wa.x; a0.y += ev.y * wa.y; a0.z += ev.y * wa.z; a0.w += ev.y * wa.w;
        a1.x += ev.y * wb.x; a1.y += ev.y * wb.y; a1.z += ev.y * wb.z; a1.w += ev.y * wb.w;
        wa = *(const float4*)(w1p + 2 * HH); wb = *(const float4*)(w1p + 2 * HH + 4);
        a0.x += ev.z * wa.x; a0.y += ev.z * wa.y; a0.z += ev.z * wa.z; a0.w += ev.z * wa.w;
        a1.x += ev.z * wb.x; a1.y += ev.z * wb.y; a1.z += ev.z * wb.z; a1.w += ev.z * wb.w;
        wa = *(const float4*)(w1p + 3 * HH); wb = *(const float4*)(w1p + 3 * HH + 4);
        a0.x += ev.w * wa.x; a0.y += ev.w * wa.y; a0.z += ev.w * wa.z; a0.w += ev.w * wa.w;
        a1.x += ev.w * wb.x; a1.y += ev.w * wb.y; a1.z += ev.w * wb.z; a1.w += ev.w * wb.w;
      }
      *(float4*)(&E[tt * EST + ks])     = a0;
      *(float4*)(&E[tt * EST + ks + 4]) = a1;
    }
  }
  xloc[u] = x[b * (TT * 2) + u];

  // ---------------- persistent registers ----------------
  // Apre: thread (kq = u>>7, cs = u&127) owns cols 4cs..4cs+3, k in [32kq,+32)
  const int kq = u >> 7;
  const int cs = u & 127;
  float4 wr4[32];
  #pragma unroll
  for (int i = 0; i < 32; ++i)
    wr4[i] = *(const float4*)(Wr + (32 * kq + i) * 512 + 4 * cs);
  // Gates: lanes 0..31 of waves 0..3 own unit m = 32w+lane (SIMD-balanced)
  const int m = 32 * (w & 3) + (lane & 31);
  float wkA[4], wkB[4], bbg[4];
  #pragma unroll
  for (int gg = 0; gg < 4; ++gg) {
    wkA[gg] = Wk[gg * HH + m];
    wkB[gg] = Wk[512 + gg * HH + m];
    bbg[gg] = bias[gg * HH + m];
  }
  float c = c0[b * HH + m];
  // Phase C (wave-local): lane -> kk = lane&15, jq = lane>>4
  const int kk = lane & 15;
  const int jq = lane >> 4;
  float w2local[32];                 // W2[32jq+i][16w+kk]
  #pragma unroll
  for (int i = 0; i < 32; ++i)
    w2local[i] = W2[(32 * jq + i) * HH + 16 * w + kk];
  // Phase D: v2 for k = 16w+i via loop-invariant readlane
  const float v2r = -2.0f * V[16 * w + kk];
  float vL[16];
  #pragma unroll
  for (int i = 0; i < 16; ++i) vL[i] = rdlane(v2r, i);
  float ptr0 = 1.0f, ptr1 = 1.0f;
  float svr;
  {
    float v = V[lane] + V[64 + lane];
    #pragma unroll
    for (int o = 1; o < 64; o <<= 1) v += __shfl_xor(v, o, 64);
    svr = v;
  }

  __syncthreads();   // P0 staging + xloc visible

  // ---------------- P1: E = exp2(C2 * enc_proj) in place (own chunks) ----------
  {
    float* Er = &E[(u >> 1) * EST + 64 * (u & 1)];
    #pragma unroll
    for (int i = 0; i < 16; ++i) {
      float4 ev = *(const float4*)(Er + 4 * i);
      ev.x = __builtin_amdgcn_exp2f(ev.x * C2);
      ev.y = __builtin_amdgcn_exp2f(ev.y * C2);
      ev.z = __builtin_amdgcn_exp2f(ev.z * C2);
      ev.w = __builtin_amdgcn_exp2f(ev.w * C2);
      *(float4*)(Er + 4 * i) = ev;
    }
  }
  // prologue Apre: zpart = h0 @ Wr (h0 from global; hbuf untouched -> no race)
  {
    float hA0 = h0[(size_t)b * HH + 32 * kq + (lane & 31)];
    float4 zac = {0.f, 0.f, 0.f, 0.f};
    #pragma unroll
    for (int i = 0; i < 32; ++i) {
      float hi = rdlane(hA0, i);
      zac.x += hi * wr4[i].x;
      zac.y += hi * wr4[i].y;
      zac.z += hi * wr4[i].z;
      zac.w += hi * wr4[i].w;
    }
    *(float4*)(&zpart[kq * 512 + 4 * cs]) = zac;
  }
  __syncthreads();   // E final + zpart(h0) visible

  float* outb = out + (size_t)b * TT * TT;

  // ---------------- step loop: 2 barriers ----------------
  #pragma unroll 1
  for (int step = 0; step < TT; ++step) {
    // ==== R window: reduce scores(step-1) -> out row + ptr; gates -> h_step ====
    if (step > 0 && w < 4) {
      float4 sc = {0.f, 0.f, 0.f, 0.f};
      #pragma unroll
      for (int q = 0; q < 8; ++q) {
        float4 v = *(const float4*)(&scp[q * SCPS + 4 * lane]);
        sc.x += v.x; sc.y += v.y; sc.z += v.z; sc.w += v.w;
      }
      sc.x += svr; sc.y += svr; sc.z += svr; sc.w += svr;
      // fixed-shift softmax numerators (|score| <= ~10.5; shift-invariant)
      float p0 = __builtin_amdgcn_exp2f((sc.x - 12.0f) * L2E);
      float p1 = __builtin_amdgcn_exp2f((sc.y - 12.0f) * L2E);
      float p2 = __builtin_amdgcn_exp2f((sc.z - 12.0f) * L2E);
      float p3 = __builtin_amdgcn_exp2f((sc.w - 12.0f) * L2E);
      float m4 = fmaxf(fmaxf(sc.x, sc.y), fmaxf(sc.z, sc.w));
      int ttl = (sc.x == m4) ? 0 : (sc.y == m4) ? 1 : (sc.z == m4) ? 2 : 3;
      float ws4 = (p0 + p1) + (p2 + p3);
      float mx = m4;
      #pragma unroll
      for (int o = 1; o < 64; o <<= 1) {
        mx  = fmaxf(mx, __shfl_xor(mx, o));
        ws4 += __shfl_xor(ws4, o);
      }
      unsigned long long bal = __ballot(m4 == mx);
      int ls  = __ffsll(bal) - 1;              // first-max lane = lowest t block
      int tc  = 4 * lane + ttl;
      int tts = __builtin_amdgcn_readlane(tc, ls);
      ptr0 = xloc[2 * tts + 0];
      ptr1 = xloc[2 * tts + 1];
      if ((lane >> 4) == w) {                  // wave w writes t in [64w,64w+64)
        float rs = __builtin_amdgcn_rcpf(ws4);
        float4 po = {p0 * rs, p1 * rs, p2 * rs, p3 * rs};
        *(float4*)(&outb[(size_t)(step - 1) * TT + 4 * lane]) = po;
      }
    }
    if ((lane & 32) == 0 && w < 4) {   // gates: unit m=32w+lane, all 4 gates
      float z0 = bbg[0] + ptr0 * wkA[0] + ptr1 * wkB[0];
      float z1 = bbg[1] + ptr0 * wkA[1] + ptr1 * wkB[1];
      float z2 = bbg[2] + ptr0 * wkA[2] + ptr1 * wkB[2];
      float z3 = bbg[3] + ptr0 * wkA[3] + ptr1 * wkB[3];
      #pragma unroll
      for (int q = 0; q < 4; ++q) {
        z0 += zpart[q * 512 + 0 * HH + m];
        z1 += zpart[q * 512 + 1 * HH + m];
        z2 += zpart[q * 512 + 2 * HH + m];
        z3 += zpart[q * 512 + 3 * HH + m];
      }
      float ig = fast_sigmoid(z0);
      float fg = fast_sigmoid(z1);
      float gg = fast_tanh(z2);
      float og = fast_sigmoid(z3);
      c = fg * c + ig * gg;
      hbuf[m] = og * fast_tanh(c);
    }
    __syncthreads();                 // (W1) h_step visible

    // ==== merged window: C (wave-local u_k) + U + D + Apre ====
    // C: lane (kk,jq) partial over j in [32jq,+32); finish with xor-16/32.
    float Uk;
    {
      float cp0 = 0.0f, cp1 = 0.0f;
      const float4* h4 = (const float4*)(hbuf + 32 * jq);
      #pragma unroll
      for (int i4 = 0; i4 < 8; ++i4) {
        float4 hv = h4[i4];
        cp0 += hv.x * w2local[4 * i4 + 0];
        cp1 += hv.y * w2local[4 * i4 + 1];
        cp0 += hv.z * w2local[4 * i4 + 2];
        cp1 += hv.w * w2local[4 * i4 + 3];
      }
      float csum = cp0 + cp1;
      csum += __shfl_xor(csum, 16);
      csum += __shfl_xor(csum, 32);
      Uk = __builtin_amdgcn_exp2f(csum * C2);
    }
    // D: wave w, k in [16w,+16); lane owns t in {lane,64+,128+,192+}
    {
      float uL[16];
      #pragma unroll
      for (int i = 0; i < 16; ++i) uL[i] = rdlane(Uk, i);
      #pragma unroll
      for (int tt = 0; tt < 4; ++tt) {
        const float* Er = &E[(64 * tt + lane) * EST + 16 * w];
        float4 e0 = *(const float4*)(Er + 0);
        float4 e1 = *(const float4*)(Er + 4);
        float4 e2 = *(const float4*)(Er + 8);
        float4 e3 = *(const float4*)(Er + 12);
        float a0 = 0.0f, a1 = 0.0f;
        float t0, t1, n;
        t0 = fmaf(e0.x, uL[ 0], 1.0f); t1 = fmaf(e0.y, uL[ 1], 1.0f);
        n  = fmaf(vL[ 1], t0, vL[ 0] * t1);
        a0 = fmaf(n, __builtin_amdgcn_rcpf(t0 * t1), a0);
        t0 = fmaf(e0.z, uL[ 2], 1.0f); t1 = fmaf(e0.w, uL[ 3], 1.0f);
        n  = fmaf(vL[ 3], t0, vL[ 2] * t1);
        a1 = fmaf(n, __builtin_amdgcn_rcpf(t0 * t1), a1);
        t0 = fmaf(e1.x, uL[ 4], 1.0f); t1 = fmaf(e1.y, uL[ 5], 1.0f);
        n  = fmaf(vL[ 5], t0, vL[ 4] * t1);
        a0 = fmaf(n, __builtin_amdgcn_rcpf(t0 * t1), a0);
        t0 = fmaf(e1.z, uL[ 6], 1.0f); t1 = fmaf(e1.w, uL[ 7], 1.0f);
        n  = fmaf(vL[ 7], t0, vL[ 6] * t1);
        a1 = fmaf(n, __builtin_amdgcn_rcpf(t0 * t1), a1);
        t0 = fmaf(e2.x, uL[ 8], 1.0f); t1 = fmaf(e2.y, uL[ 9], 1.0f);
        n  = fmaf(vL[ 9], t0, vL[ 8] * t1);
        a0 = fmaf(n, __builtin_amdgcn_rcpf(t0 * t1), a0);
        t0 = fmaf(e2.z, uL[10], 1.0f); t1 = fmaf(e2.w, uL[11], 1.0f);
        n  = fmaf(vL[11], t0, vL[10] * t1);
        a1 = fmaf(n, __builtin_amdgcn_rcpf(t0 * t1), a1);
        t0 = fmaf(e3.x, uL[12], 1.0f); t1 = fmaf(e3.y, uL[13], 1.0f);
        n  = fmaf(vL[13], t0, vL[12] * t1);
        a0 = fmaf(n, __builtin_amdgcn_rcpf(t0 * t1), a0);
        t0 = fmaf(e3.z, uL[14], 1.0f); t1 = fmaf(e3.w, uL[15], 1.0f);
        n  = fmaf(vL[15], t0, vL[14] * t1);
        a1 = fmaf(n, __builtin_amdgcn_rcpf(t0 * t1), a1);
        scp[w * SCPS + 64 * tt + lane] = a0 + a1;
      }
    }
    // Apre: zpart = h_step @ Wr (fmac-heavy; co-issues with D's rcp tail)
    {
      float hA = hbuf[32 * kq + (lane & 31)];
      float4 zac = {0.f, 0.f, 0.f, 0.f};
      #pragma unroll
      for (int i = 0; i < 32; ++i) {
        float hi = rdlane(hA, i);
        zac.x += hi * wr4[i].x;
        zac.y += hi * wr4[i].y;
        zac.z += hi * wr4[i].z;
        zac.w += hi * wr4[i].w;
      }
      *(float4*)(&zpart[kq * 512 + 4 * cs]) = zac;
    }
    __syncthreads();                 // (W3) scp + zpart visible
  }

  // ---------------- peel: reduce + store final row (step 255) ----------------
  if (w < 4) {
    float4 sc = {0.f, 0.f, 0.f, 0.f};
    #pragma unroll
    for (int q = 0; q < 8; ++q) {
      float4 v = *(const float4*)(&scp[q * SCPS + 4 * lane]);
      sc.x += v.x; sc.y += v.y; sc.z += v.z; sc.w += v.w;
    }
    sc.x += svr; sc.y += svr; sc.z += svr; sc.w += svr;
    float p0 = __builtin_amdgcn_exp2f((sc.x - 12.0f) * L2E);
    float p1 = __builtin_amdgcn_exp2f((sc.y - 12.0f) * L2E);
    float p2 = __builtin_amdgcn_exp2f((sc.z - 12.0f) * L2E);
    float p3 = __builtin_amdgcn_exp2f((sc.w - 12.0f) * L2E);
    float ws4 = (p0 + p1) + (p2 + p3);
    #pragma unroll
    for (int o = 1; o < 64; o <<= 1) ws4 += __shfl_xor(ws4, o);
    if ((lane >> 4) == w) {
      float rs = __builtin_amdgcn_rcpf(ws4);
      float4 po = {p0 * rs, p1 * rs, p2 * rs, p3 * rs};
      *(float4*)(&outb[(size_t)255 * TT + 4 * lane]) = po;
    }
  }
}

extern "C" void kernel_launch(void* const* d_in, const int* in_sizes, int n_in,
                              void* d_out, int out_size, void* d_ws, size_t ws_size,
                              hipStream_t stream) {
  (void)in_sizes; (void)n_in; (void)d_ws; (void)ws_size; (void)out_size;
  const float* x    = (const float*)d_in[0];
  const float* enc  = (const float*)d_in[1];
  const float* h0   = (const float*)d_in[2];
  const float* c0   = (const float*)d_in[3];
  const float* W1   = (const float*)d_in[4];
  const float* W2   = (const float*)d_in[5];
  const float* V    = (const float*)d_in[6];
  const float* Wk   = (const float*)d_in[7];
  const float* Wr   = (const float*)d_in[8];
  const float* bias = (const float*)d_in[9];
  float* out = (float*)d_out;

  decoder_kernel<<<64, 512, 0, stream>>>(x, enc, h0, c0, W1, W2, V, Wk, Wr, bias, out);
}

// Round 12
// 809.382 us; speedup vs baseline: 1.2510x; 1.0294x over previous
//
#include <hip/hip_runtime.h>
#include <cstddef>

#define TT 256
#define HH 128
#define EST 132    // E row stride: b128 reads land 8 dwords on every bank = balanced
#define SCPS 260   // scp row stride: 16B-aligned rows, banks balanced

__device__ __forceinline__ float rdlane(float v, int l) {
  return __int_as_float(__builtin_amdgcn_readlane(__float_as_int(v), l));
}
__device__ __forceinline__ float fast_sigmoid(float x) {
  const float L2E = 1.4426950408889634f;
  float y = __builtin_amdgcn_exp2f(-x * L2E);
  return __builtin_amdgcn_rcpf(1.0f + y);
}
__device__ __forceinline__ float fast_tanh(float x) {
  const float C2 = 2.8853900817779268f;   // 2*log2(e)
  float y = __builtin_amdgcn_exp2f(x * C2);
  return 1.0f - 2.0f * __builtin_amdgcn_rcpf(1.0f + y);
}

// One workgroup per batch element; 512 threads = 8 waves (2/SIMD).
// 2 barriers/step. R window split by role:
//   waves 0-3: scp-reduce -> argmax -> ptr -> gates (the recurrence path)
//   waves 4-7: scp-reduce -> softmax -> out-row store (off the critical path)
// Fat window: C (wave-local u_k) + U + D + Apre, as R11.
__global__ __launch_bounds__(512, 2)
void decoder_kernel(const float* __restrict__ x,
                    const float* __restrict__ enc_output,
                    const float* __restrict__ h0,
                    const float* __restrict__ c0,
                    const float* __restrict__ W1,
                    const float* __restrict__ W2,
                    const float* __restrict__ V,
                    const float* __restrict__ Wk,
                    const float* __restrict__ Wr,
                    const float* __restrict__ bias,
                    float* __restrict__ out)
{
  __shared__ float E[TT * EST];      // 135168 B : exp2(C2 * enc_proj)
  __shared__ float zpart[4 * 512];   // 8192 B   : h@Wr k-quarter partials
  __shared__ float scp[8 * SCPS];    // 8320 B   : phase-D partials [kgroup][t]
  __shared__ float hbuf[HH];         // 512 B
  // total 152192 B <= 160 KiB

  const int u    = threadIdx.x;
  const int b    = blockIdx.x;
  const int lane = u & 63;
  const int w    = u >> 6;           // wave 0..7 (owns k in [16w,16w+16) for C/D)
  const float C2  = 2.8853900817779268f;
  const float L2E = 1.4426950408889634f;

  // ---------------- P0: enc_proj = enc_output[b] @ W1 -> E (raw) ----------------
  {
    const float* encb = enc_output + (size_t)b * TT * HH;
    const int tsub = u >> 4;
    const int ks   = (u & 15) * 8;
    for (int p = 0; p < 8; ++p) {
      const int tt = p * 32 + tsub;
      float4 a0 = {0.f, 0.f, 0.f, 0.f};
      float4 a1 = {0.f, 0.f, 0.f, 0.f};
      const float4* er4 = (const float4*)(encb + tt * HH);
      for (int j4 = 0; j4 < 32; ++j4) {
        const float4 ev = er4[j4];
        const float* w1p = W1 + (j4 * 4) * HH + ks;
        float4 wa, wb;
        wa = *(const float4*)(w1p + 0 * HH); wb = *(const float4*)(w1p + 0 * HH + 4);
        a0.x += ev.x * wa.x; a0.y += ev.x * wa.y; a0.z += ev.x * wa.z; a0.w += ev.x * wa.w;
        a1.x += ev.x * wb.x; a1.y += ev.x * wb.y; a1.z += ev.x * wb.z; a1.w += ev.x * wb.w;
        wa = *(const float4*)(w1p + 1 * HH); wb = *(const float4*)(w1p + 1 * HH + 4);
        a0.x += ev.y * wa.x; a0.y += ev.y * wa.y; a0.z += ev.y * wa.z; a0.w += ev.y * wa.w;
        a1.x += ev.y * wb.x; a1.y += ev.y * wb.y; a1.z += ev.y * wb.z; a1.w += ev.y * wb.w;
        wa = *(const float4*)(w1p + 2 * HH); wb = *(const float4*)(w1p + 2 * HH + 4);
        a0.x += ev.z * wa.x; a0.y += ev.z * wa.y; a0.z += ev.z * wa.z; a0.w += ev.z * wa.w;
        a1.x += ev.z * wb.x; a1.y += ev.z * wb.y; a1.z += ev.z * wb.z; a1.w += ev.z * wb.w;
        wa = *(const float4*)(w1p + 3 * HH); wb = *(const float4*)(w1p + 3 * HH + 4);
        a0.x += ev.w * wa.x; a0.y += ev.w * wa.y; a0.z += ev.w * wa.z; a0.w += ev.w * wa.w;
        a1.x += ev.w * wb.x; a1.y += ev.w * wb.y; a1.z += ev.w * wb.z; a1.w += ev.w * wb.w;
      }
      *(float4*)(&E[tt * EST + ks])     = a0;
      *(float4*)(&E[tt * EST + ks + 4]) = a1;
    }
  }

  // ---------------- persistent registers ----------------
  // Apre: thread (kq = u>>7, cs = u&127) owns cols 4cs..4cs+3, k in [32kq,+32)
  const int kq = u >> 7;             // wave-uniform (w>>1)
  const int cs = u & 127;
  float4 wr4[32];
  #pragma unroll
  for (int i = 0; i < 32; ++i)
    wr4[i] = *(const float4*)(Wr + (32 * kq + i) * 512 + 4 * cs);
  // Gates: lanes 0..31 of waves 0..3 own unit m = 32w+lane (SIMD-balanced)
  const int m = 32 * (w & 3) + (lane & 31);
  float wkA[4], wkB[4], bbg[4];
  #pragma unroll
  for (int gg = 0; gg < 4; ++gg) {
    wkA[gg] = Wk[gg * HH + m];
    wkB[gg] = Wk[512 + gg * HH + m];
    bbg[gg] = bias[gg * HH + m];
  }
  float c = c0[b * HH + m];
  // x pairs in registers: lane holds t = 64j + lane, j = 0..3
  float2 xr0 = *(const float2*)(x + b * (TT * 2) + 2 * (0 * 64 + lane));
  float2 xr1 = *(const float2*)(x + b * (TT * 2) + 2 * (1 * 64 + lane));
  float2 xr2 = *(const float2*)(x + b * (TT * 2) + 2 * (2 * 64 + lane));
  float2 xr3 = *(const float2*)(x + b * (TT * 2) + 2 * (3 * 64 + lane));
  // Phase C (wave-local): lane -> kk = lane&15, jq = lane>>4
  const int kk = lane & 15;
  const int jq = lane >> 4;
  float w2local[32];                 // W2[32jq+i][16w+kk]
  #pragma unroll
  for (int i = 0; i < 32; ++i)
    w2local[i] = W2[(32 * jq + i) * HH + 16 * w + kk];
  // Phase D: v2 for k = 16w+i via loop-invariant readlane
  const float v2r = -2.0f * V[16 * w + kk];
  float vL[16];
  #pragma unroll
  for (int i = 0; i < 16; ++i) vL[i] = rdlane(v2r, i);
  float ptr0 = 1.0f, ptr1 = 1.0f;
  float svr;
  {
    float v = V[lane] + V[64 + lane];
    #pragma unroll
    for (int o = 1; o < 64; o <<= 1) v += __shfl_xor(v, o, 64);
    svr = v;
  }

  __syncthreads();   // P0 staging visible

  // ---------------- P1: E = exp2(C2 * enc_proj) in place (own chunks) ----------
  {
    float* Er = &E[(u >> 1) * EST + 64 * (u & 1)];
    #pragma unroll
    for (int i = 0; i < 16; ++i) {
      float4 ev = *(const float4*)(Er + 4 * i);
      ev.x = __builtin_amdgcn_exp2f(ev.x * C2);
      ev.y = __builtin_amdgcn_exp2f(ev.y * C2);
      ev.z = __builtin_amdgcn_exp2f(ev.z * C2);
      ev.w = __builtin_amdgcn_exp2f(ev.w * C2);
      *(float4*)(Er + 4 * i) = ev;
    }
  }
  // prologue Apre: zpart = h0 @ Wr (h0 from global; hbuf untouched -> no race)
  {
    float hA0 = h0[(size_t)b * HH + 32 * kq + (lane & 31)];
    float4 zac = {0.f, 0.f, 0.f, 0.f};
    #pragma unroll
    for (int i = 0; i < 32; ++i) {
      float hi = rdlane(hA0, i);
      zac.x += hi * wr4[i].x;
      zac.y += hi * wr4[i].y;
      zac.z += hi * wr4[i].z;
      zac.w += hi * wr4[i].w;
    }
    *(float4*)(&zpart[kq * 512 + 4 * cs]) = zac;
  }
  __syncthreads();   // E final + zpart(h0) visible

  float* outb = out + (size_t)b * TT * TT;

  // ---------------- step loop: 2 barriers ----------------
  #pragma unroll 1
  for (int step = 0; step < TT; ++step) {
    // ==== R window ====
    if (step > 0) {
      // both halves: reduce scores for t = 4*lane .. 4*lane+3
      float4 sc = {0.f, 0.f, 0.f, 0.f};
      #pragma unroll
      for (int q = 0; q < 8; ++q) {
        float4 v = *(const float4*)(&scp[q * SCPS + 4 * lane]);
        sc.x += v.x; sc.y += v.y; sc.z += v.z; sc.w += v.w;
      }
      if (w < 4) {
        // ---- argmax path (critical): mx -> ballot -> ptr (regs) -> gates ----
        float m4 = fmaxf(fmaxf(sc.x, sc.y), fmaxf(sc.z, sc.w));
        int ttl = (sc.x == m4) ? 0 : (sc.y == m4) ? 1 : (sc.z == m4) ? 2 : 3;
        float mx = m4;
        #pragma unroll
        for (int o = 1; o < 64; o <<= 1) mx = fmaxf(mx, __shfl_xor(mx, o));
        unsigned long long bal = __ballot(m4 == mx);
        int ls  = __ffsll(bal) - 1;            // first-max lane = lowest t block
        int tc  = 4 * lane + ttl;
        int tts = __builtin_amdgcn_readlane(tc, ls);   // wave-uniform winner t
        int j   = tts >> 6;                    // uniform
        int ll  = tts & 63;                    // uniform
        float2 cand = (j == 0) ? xr0 : (j == 1) ? xr1 : (j == 2) ? xr2 : xr3;
        ptr0 = rdlane(cand.x, ll);
        ptr1 = rdlane(cand.y, ll);
      } else {
        // ---- softmax path (off critical): p -> ws -> out-row store ----
        sc.x += svr; sc.y += svr; sc.z += svr; sc.w += svr;
        float p0 = __builtin_amdgcn_exp2f((sc.x - 12.0f) * L2E);
        float p1 = __builtin_amdgcn_exp2f((sc.y - 12.0f) * L2E);
        float p2 = __builtin_amdgcn_exp2f((sc.z - 12.0f) * L2E);
        float p3 = __builtin_amdgcn_exp2f((sc.w - 12.0f) * L2E);
        float ws4 = (p0 + p1) + (p2 + p3);
        #pragma unroll
        for (int o = 1; o < 64; o <<= 1) ws4 += __shfl_xor(ws4, o);
        if ((lane >> 4) == (w - 4)) {          // wave 4+i writes t in [64i,64i+64)
          float rs = __builtin_amdgcn_rcpf(ws4);
          float4 po = {p0 * rs, p1 * rs, p2 * rs, p3 * rs};
          *(float4*)(&outb[(size_t)(step - 1) * TT + 4 * lane]) = po;
        }
      }
    }
    if ((lane & 32) == 0 && w < 4) {   // gates: unit m=32w+lane, all 4 gates
      float z0 = bbg[0] + ptr0 * wkA[0] + ptr1 * wkB[0];
      float z1 = bbg[1] + ptr0 * wkA[1] + ptr1 * wkB[1];
      float z2 = bbg[2] + ptr0 * wkA[2] + ptr1 * wkB[2];
      float z3 = bbg[3] + ptr0 * wkA[3] + ptr1 * wkB[3];
      #pragma unroll
      for (int q = 0; q < 4; ++q) {
        z0 += zpart[q * 512 + 0 * HH + m];
        z1 += zpart[q * 512 + 1 * HH + m];
        z2 += zpart[q * 512 + 2 * HH + m];
        z3 += zpart[q * 512 + 3 * HH + m];
      }
      float ig = fast_sigmoid(z0);
      float fg = fast_sigmoid(z1);
      float gg = fast_tanh(z2);
      float og = fast_sigmoid(z3);
      c = fg * c + ig * gg;
      hbuf[m] = og * fast_tanh(c);
    }
    __syncthreads();                 // (W1) h_step visible

    // ==== fat window: C (wave-local u_k) + U + D + Apre ====
    float Uk;
    {
      float cp0 = 0.0f, cp1 = 0.0f;
      const float4* h4 = (const float4*)(hbuf + 32 * jq);
      #pragma unroll
      for (int i4 = 0; i4 < 8; ++i4) {
        float4 hv = h4[i4];
        cp0 += hv.x * w2local[4 * i4 + 0];
        cp1 += hv.y * w2local[4 * i4 + 1];
        cp0 += hv.z * w2local[4 * i4 + 2];
        cp1 += hv.w * w2local[4 * i4 + 3];
      }
      float csum = cp0 + cp1;
      csum += __shfl_xor(csum, 16);
      csum += __shfl_xor(csum, 32);
      Uk = __builtin_amdgcn_exp2f(csum * C2);
    }
    // D: wave w, k in [16w,+16); lane owns t in {lane,64+,128+,192+}
    {
      float uL[16];
      #pragma unroll
      for (int i = 0; i < 16; ++i) uL[i] = rdlane(Uk, i);
      #pragma unroll
      for (int tt = 0; tt < 4; ++tt) {
        const float* Er = &E[(64 * tt + lane) * EST + 16 * w];
        float4 e0 = *(const float4*)(Er + 0);
        float4 e1 = *(const float4*)(Er + 4);
        float4 e2 = *(const float4*)(Er + 8);
        float4 e3 = *(const float4*)(Er + 12);
        float a0 = 0.0f, a1 = 0.0f;
        float t0, t1, n;
        t0 = fmaf(e0.x, uL[ 0], 1.0f); t1 = fmaf(e0.y, uL[ 1], 1.0f);
        n  = fmaf(vL[ 1], t0, vL[ 0] * t1);
        a0 = fmaf(n, __builtin_amdgcn_rcpf(t0 * t1), a0);
        t0 = fmaf(e0.z, uL[ 2], 1.0f); t1 = fmaf(e0.w, uL[ 3], 1.0f);
        n  = fmaf(vL[ 3], t0, vL[ 2] * t1);
        a1 = fmaf(n, __builtin_amdgcn_rcpf(t0 * t1), a1);
        t0 = fmaf(e1.x, uL[ 4], 1.0f); t1 = fmaf(e1.y, uL[ 5], 1.0f);
        n  = fmaf(vL[ 5], t0, vL[ 4] * t1);
        a0 = fmaf(n, __builtin_amdgcn_rcpf(t0 * t1), a0);
        t0 = fmaf(e1.z, uL[ 6], 1.0f); t1 = fmaf(e1.w, uL[ 7], 1.0f);
        n  = fmaf(vL[ 7], t0, vL[ 6] * t1);
        a1 = fmaf(n, __builtin_amdgcn_rcpf(t0 * t1), a1);
        t0 = fmaf(e2.x, uL[ 8], 1.0f); t1 = fmaf(e2.y, uL[ 9], 1.0f);
        n  = fmaf(vL[ 9], t0, vL[ 8] * t1);
        a0 = fmaf(n, __builtin_amdgcn_rcpf(t0 * t1), a0);
        t0 = fmaf(e2.z, uL[10], 1.0f); t1 = fmaf(e2.w, uL[11], 1.0f);
        n  = fmaf(vL[11], t0, vL[10] * t1);
        a1 = fmaf(n, __builtin_amdgcn_rcpf(t0 * t1), a1);
        t0 = fmaf(e3.x, uL[12], 1.0f); t1 = fmaf(e3.y, uL[13], 1.0f);
        n  = fmaf(vL[13], t0, vL[12] * t1);
        a0 = fmaf(n, __builtin_amdgcn_rcpf(t0 * t1), a0);
        t0 = fmaf(e3.z, uL[14], 1.0f); t1 = fmaf(e3.w, uL[15], 1.0f);
        n  = fmaf(vL[15], t0, vL[14] * t1);
        a1 = fmaf(n, __builtin_amdgcn_rcpf(t0 * t1), a1);
        scp[w * SCPS + 64 * tt + lane] = a0 + a1;
      }
    }
    // Apre: zpart = h_step @ Wr; h via broadcast b128 reads (kq wave-uniform)
    {
      const float4* h4 = (const float4*)(hbuf + 32 * kq);
      float4 zac = {0.f, 0.f, 0.f, 0.f};
      #pragma unroll
      for (int i4 = 0; i4 < 8; ++i4) {
        float4 hv = h4[i4];
        zac.x += hv.x * wr4[4 * i4 + 0].x;
        zac.y += hv.x * wr4[4 * i4 + 0].y;
        zac.z += hv.x * wr4[4 * i4 + 0].z;
        zac.w += hv.x * wr4[4 * i4 + 0].w;
        zac.x += hv.y * wr4[4 * i4 + 1].x;
        zac.y += hv.y * wr4[4 * i4 + 1].y;
        zac.z += hv.y * wr4[4 * i4 + 1].z;
        zac.w += hv.y * wr4[4 * i4 + 1].w;
        zac.x += hv.z * wr4[4 * i4 + 2].x;
        zac.y += hv.z * wr4[4 * i4 + 2].y;
        zac.z += hv.z * wr4[4 * i4 + 2].z;
        zac.w += hv.z * wr4[4 * i4 + 2].w;
        zac.x += hv.w * wr4[4 * i4 + 3].x;
        zac.y += hv.w * wr4[4 * i4 + 3].y;
        zac.z += hv.w * wr4[4 * i4 + 3].z;
        zac.w += hv.w * wr4[4 * i4 + 3].w;
      }
      *(float4*)(&zpart[kq * 512 + 4 * cs]) = zac;
    }
    __syncthreads();                 // (W3) scp + zpart visible
  }

  // ---------------- peel: reduce + store final row (step 255) ----------------
  if (w >= 4) {
    float4 sc = {0.f, 0.f, 0.f, 0.f};
    #pragma unroll
    for (int q = 0; q < 8; ++q) {
      float4 v = *(const float4*)(&scp[q * SCPS + 4 * lane]);
      sc.x += v.x; sc.y += v.y; sc.z += v.z; sc.w += v.w;
    }
    sc.x += svr; sc.y += svr; sc.z += svr; sc.w += svr;
    float p0 = __builtin_amdgcn_exp2f((sc.x - 12.0f) * L2E);
    float p1 = __builtin_amdgcn_exp2f((sc.y - 12.0f) * L2E);
    float p2 = __builtin_amdgcn_exp2f((sc.z - 12.0f) * L2E);
    float p3 = __builtin_amdgcn_exp2f((sc.w - 12.0f) * L2E);
    float ws4 = (p0 + p1) + (p2 + p3);
    #pragma unroll
    for (int o = 1; o < 64; o <<= 1) ws4 += __shfl_xor(ws4, o);
    if ((lane >> 4) == (w - 4)) {
      float rs = __builtin_amdgcn_rcpf(ws4);
      float4 po = {p0 * rs, p1 * rs, p2 * rs, p3 * rs};
      *(float4*)(&outb[(size_t)255 * TT + 4 * lane]) = po;
    }
  }
}

extern "C" void kernel_launch(void* const* d_in, const int* in_sizes, int n_in,
                              void* d_out, int out_size, void* d_ws, size_t ws_size,
                              hipStream_t stream) {
  (void)in_sizes; (void)n_in; (void)d_ws; (void)ws_size; (void)out_size;
  const float* x    = (const float*)d_in[0];
  const float* enc  = (const float*)d_in[1];
  const float* h0   = (const float*)d_in[2];
  const float* c0   = (const float*)d_in[3];
  const float* W1   = (const float*)d_in[4];
  const float* W2   = (const float*)d_in[5];
  const float* V    = (const float*)d_in[6];
  const float* Wk   = (const float*)d_in[7];
  const float* Wr   = (const float*)d_in[8];
  const float* bias = (const float*)d_in[9];
  float* out = (float*)d_out;

  decoder_kernel<<<64, 512, 0, stream>>>(x, enc, h0, c0, W1, W2, V, Wk, Wr, bias, out);
}

// Round 13
// 807.816 us; speedup vs baseline: 1.2534x; 1.0019x over previous
//
#include <hip/hip_runtime.h>
#include <cstddef>

#define TT 256
#define HH 128
#define EST 132    // E row stride: b128 reads land 8 dwords on every bank = balanced
#define SCPS 260   // scp row stride: 16B-aligned rows, banks balanced

__device__ __forceinline__ float rdlane(float v, int l) {
  return __int_as_float(__builtin_amdgcn_readlane(__float_as_int(v), l));
}
__device__ __forceinline__ float fast_sigmoid(float x) {
  const float L2E = 1.4426950408889634f;
  float y = __builtin_amdgcn_exp2f(-x * L2E);
  return __builtin_amdgcn_rcpf(1.0f + y);
}
__device__ __forceinline__ float fast_tanh(float x) {
  const float C2 = 2.8853900817779268f;   // 2*log2(e)
  float y = __builtin_amdgcn_exp2f(x * C2);
  return 1.0f - 2.0f * __builtin_amdgcn_rcpf(1.0f + y);
}

// One workgroup per batch element; 512 threads = 8 waves (2/SIMD).
// Occupancy is LDS-pinned to 1 WG/CU (152 KB), so 2 waves/SIMD is the ONLY
// achievable occupancy -> amdgpu_waves_per_eu(2,2) licenses the allocator to
// use the full 256 arch-VGPR budget. R12's __launch_bounds__(512,2) left the
// ~240-reg persistent set split 120 VGPR + ~120 AGPR, taxing every Apre/D MAC
// with v_accvgpr_read (VGPR_Count=120 while static set ~240).
__global__ __attribute__((amdgpu_flat_work_group_size(512, 512),
                          amdgpu_waves_per_eu(2, 2)))
void decoder_kernel(const float* __restrict__ x,
                    const float* __restrict__ enc_output,
                    const float* __restrict__ h0,
                    const float* __restrict__ c0,
                    const float* __restrict__ W1,
                    const float* __restrict__ W2,
                    const float* __restrict__ V,
                    const float* __restrict__ Wk,
                    const float* __restrict__ Wr,
                    const float* __restrict__ bias,
                    float* __restrict__ out)
{
  __shared__ float E[TT * EST];      // 135168 B : exp2(C2 * enc_proj)
  __shared__ float zpart[4 * 512];   // 8192 B   : h@Wr k-quarter partials
  __shared__ float scp[8 * SCPS];    // 8320 B   : phase-D partials [kgroup][t]
  __shared__ float hbuf[HH];         // 512 B
  // total 152192 B <= 160 KiB

  const int u    = threadIdx.x;
  const int b    = blockIdx.x;
  const int lane = u & 63;
  const int w    = u >> 6;           // wave 0..7 (owns k in [16w,16w+16) for C/D)
  const float C2  = 2.8853900817779268f;
  const float L2E = 1.4426950408889634f;

  // ---------------- P0: enc_proj = enc_output[b] @ W1 -> E (raw) ----------------
  {
    const float* encb = enc_output + (size_t)b * TT * HH;
    const int tsub = u >> 4;
    const int ks   = (u & 15) * 8;
    for (int p = 0; p < 8; ++p) {
      const int tt = p * 32 + tsub;
      float4 a0 = {0.f, 0.f, 0.f, 0.f};
      float4 a1 = {0.f, 0.f, 0.f, 0.f};
      const float4* er4 = (const float4*)(encb + tt * HH);
      for (int j4 = 0; j4 < 32; ++j4) {
        const float4 ev = er4[j4];
        const float* w1p = W1 + (j4 * 4) * HH + ks;
        float4 wa, wb;
        wa = *(const float4*)(w1p + 0 * HH); wb = *(const float4*)(w1p + 0 * HH + 4);
        a0.x += ev.x * wa.x; a0.y += ev.x * wa.y; a0.z += ev.x * wa.z; a0.w += ev.x * wa.w;
        a1.x += ev.x * wb.x; a1.y += ev.x * wb.y; a1.z += ev.x * wb.z; a1.w += ev.x * wb.w;
        wa = *(const float4*)(w1p + 1 * HH); wb = *(const float4*)(w1p + 1 * HH + 4);
        a0.x += ev.y * wa.x; a0.y += ev.y * wa.y; a0.z += ev.y * wa.z; a0.w += ev.y * wa.w;
        a1.x += ev.y * wb.x; a1.y += ev.y * wb.y; a1.z += ev.y * wb.z; a1.w += ev.y * wb.w;
        wa = *(const float4*)(w1p + 2 * HH); wb = *(const float4*)(w1p + 2 * HH + 4);
        a0.x += ev.z * wa.x; a0.y += ev.z * wa.y; a0.z += ev.z * wa.z; a0.w += ev.z * wa.w;
        a1.x += ev.z * wb.x; a1.y += ev.z * wb.y; a1.z += ev.z * wb.z; a1.w += ev.z * wb.w;
        wa = *(const float4*)(w1p + 3 * HH); wb = *(const float4*)(w1p + 3 * HH + 4);
        a0.x += ev.w * wa.x; a0.y += ev.w * wa.y; a0.z += ev.w * wa.z; a0.w += ev.w * wa.w;
        a1.x += ev.w * wb.x; a1.y += ev.w * wb.y; a1.z += ev.w * wb.z; a1.w += ev.w * wb.w;
      }
      *(float4*)(&E[tt * EST + ks])     = a0;
      *(float4*)(&E[tt * EST + ks + 4]) = a1;
    }
  }

  // ---------------- persistent registers ----------------
  // Apre: thread (kq = u>>7, cs = u&127) owns cols 4cs..4cs+3, k in [32kq,+32)
  const int kq = u >> 7;             // wave-uniform (w>>1)
  const int cs = u & 127;
  float4 wr4[32];
  #pragma unroll
  for (int i = 0; i < 32; ++i)
    wr4[i] = *(const float4*)(Wr + (32 * kq + i) * 512 + 4 * cs);
  // Gates: lanes 0..31 of waves 0..3 own unit m = 32w+lane (SIMD-balanced)
  const int m = 32 * (w & 3) + (lane & 31);
  float wkA[4], wkB[4], bbg[4];
  #pragma unroll
  for (int gg = 0; gg < 4; ++gg) {
    wkA[gg] = Wk[gg * HH + m];
    wkB[gg] = Wk[512 + gg * HH + m];
    bbg[gg] = bias[gg * HH + m];
  }
  float c = c0[b * HH + m];
  // x pairs in registers: lane holds t = 64j + lane, j = 0..3
  float2 xr0 = *(const float2*)(x + b * (TT * 2) + 2 * (0 * 64 + lane));
  float2 xr1 = *(const float2*)(x + b * (TT * 2) + 2 * (1 * 64 + lane));
  float2 xr2 = *(const float2*)(x + b * (TT * 2) + 2 * (2 * 64 + lane));
  float2 xr3 = *(const float2*)(x + b * (TT * 2) + 2 * (3 * 64 + lane));
  // Phase C (wave-local): lane -> kk = lane&15, jq = lane>>4
  const int kk = lane & 15;
  const int jq = lane >> 4;
  float w2local[32];                 // W2[32jq+i][16w+kk]
  #pragma unroll
  for (int i = 0; i < 32; ++i)
    w2local[i] = W2[(32 * jq + i) * HH + 16 * w + kk];
  // Phase D: v2 for k = 16w+i via loop-invariant readlane
  const float v2r = -2.0f * V[16 * w + kk];
  float vL[16];
  #pragma unroll
  for (int i = 0; i < 16; ++i) vL[i] = rdlane(v2r, i);
  float ptr0 = 1.0f, ptr1 = 1.0f;
  float svr;
  {
    float v = V[lane] + V[64 + lane];
    #pragma unroll
    for (int o = 1; o < 64; o <<= 1) v += __shfl_xor(v, o, 64);
    svr = v;
  }

  __syncthreads();   // P0 staging visible

  // ---------------- P1: E = exp2(C2 * enc_proj) in place (own chunks) ----------
  {
    float* Er = &E[(u >> 1) * EST + 64 * (u & 1)];
    #pragma unroll
    for (int i = 0; i < 16; ++i) {
      float4 ev = *(const float4*)(Er + 4 * i);
      ev.x = __builtin_amdgcn_exp2f(ev.x * C2);
      ev.y = __builtin_amdgcn_exp2f(ev.y * C2);
      ev.z = __builtin_amdgcn_exp2f(ev.z * C2);
      ev.w = __builtin_amdgcn_exp2f(ev.w * C2);
      *(float4*)(Er + 4 * i) = ev;
    }
  }
  // prologue Apre: zpart = h0 @ Wr (h0 from global; hbuf untouched -> no race)
  {
    float hA0 = h0[(size_t)b * HH + 32 * kq + (lane & 31)];
    float4 zac = {0.f, 0.f, 0.f, 0.f};
    #pragma unroll
    for (int i = 0; i < 32; ++i) {
      float hi = rdlane(hA0, i);
      zac.x += hi * wr4[i].x;
      zac.y += hi * wr4[i].y;
      zac.z += hi * wr4[i].z;
      zac.w += hi * wr4[i].w;
    }
    *(float4*)(&zpart[kq * 512 + 4 * cs]) = zac;
  }
  __syncthreads();   // E final + zpart(h0) visible

  float* outb = out + (size_t)b * TT * TT;

  // ---------------- step loop: 2 barriers ----------------
  #pragma unroll 1
  for (int step = 0; step < TT; ++step) {
    // ==== R window ====
    if (step > 0) {
      // both halves: reduce scores for t = 4*lane .. 4*lane+3
      float4 sc = {0.f, 0.f, 0.f, 0.f};
      #pragma unroll
      for (int q = 0; q < 8; ++q) {
        float4 v = *(const float4*)(&scp[q * SCPS + 4 * lane]);
        sc.x += v.x; sc.y += v.y; sc.z += v.z; sc.w += v.w;
      }
      if (w < 4) {
        // ---- argmax path (critical): mx -> ballot -> ptr (regs) -> gates ----
        float m4 = fmaxf(fmaxf(sc.x, sc.y), fmaxf(sc.z, sc.w));
        int ttl = (sc.x == m4) ? 0 : (sc.y == m4) ? 1 : (sc.z == m4) ? 2 : 3;
        float mx = m4;
        #pragma unroll
        for (int o = 1; o < 64; o <<= 1) mx = fmaxf(mx, __shfl_xor(mx, o));
        unsigned long long bal = __ballot(m4 == mx);
        int ls  = __ffsll(bal) - 1;            // first-max lane = lowest t block
        int tc  = 4 * lane + ttl;
        int tts = __builtin_amdgcn_readlane(tc, ls);   // wave-uniform winner t
        int j   = tts >> 6;                    // uniform
        int ll  = tts & 63;                    // uniform
        float2 cand = (j == 0) ? xr0 : (j == 1) ? xr1 : (j == 2) ? xr2 : xr3;
        ptr0 = rdlane(cand.x, ll);
        ptr1 = rdlane(cand.y, ll);
      } else {
        // ---- softmax path (off critical): p -> ws -> out-row store ----
        sc.x += svr; sc.y += svr; sc.z += svr; sc.w += svr;
        float p0 = __builtin_amdgcn_exp2f((sc.x - 12.0f) * L2E);
        float p1 = __builtin_amdgcn_exp2f((sc.y - 12.0f) * L2E);
        float p2 = __builtin_amdgcn_exp2f((sc.z - 12.0f) * L2E);
        float p3 = __builtin_amdgcn_exp2f((sc.w - 12.0f) * L2E);
        float ws4 = (p0 + p1) + (p2 + p3);
        #pragma unroll
        for (int o = 1; o < 64; o <<= 1) ws4 += __shfl_xor(ws4, o);
        if ((lane >> 4) == (w - 4)) {          // wave 4+i writes t in [64i,64i+64)
          float rs = __builtin_amdgcn_rcpf(ws4);
          float4 po = {p0 * rs, p1 * rs, p2 * rs, p3 * rs};
          *(float4*)(&outb[(size_t)(step - 1) * TT + 4 * lane]) = po;
        }
      }
    }
    if ((lane & 32) == 0 && w < 4) {   // gates: unit m=32w+lane, all 4 gates
      float z0 = bbg[0] + ptr0 * wkA[0] + ptr1 * wkB[0];
      float z1 = bbg[1] + ptr0 * wkA[1] + ptr1 * wkB[1];
      float z2 = bbg[2] + ptr0 * wkA[2] + ptr1 * wkB[2];
      float z3 = bbg[3] + ptr0 * wkA[3] + ptr1 * wkB[3];
      #pragma unroll
      for (int q = 0; q < 4; ++q) {
        z0 += zpart[q * 512 + 0 * HH + m];
        z1 += zpart[q * 512 + 1 * HH + m];
        z2 += zpart[q * 512 + 2 * HH + m];
        z3 += zpart[q * 512 + 3 * HH + m];
      }
      float ig = fast_sigmoid(z0);
      float fg = fast_sigmoid(z1);
      float gg = fast_tanh(z2);
      float og = fast_sigmoid(z3);
      c = fg * c + ig * gg;
      hbuf[m] = og * fast_tanh(c);
    }
    __syncthreads();                 // (W1) h_step visible

    // ==== fat window: C (wave-local u_k) + U + D + Apre ====
    float Uk;
    {
      float cp0 = 0.0f, cp1 = 0.0f;
      const float4* h4 = (const float4*)(hbuf + 32 * jq);
      #pragma unroll
      for (int i4 = 0; i4 < 8; ++i4) {
        float4 hv = h4[i4];
        cp0 += hv.x * w2local[4 * i4 + 0];
        cp1 += hv.y * w2local[4 * i4 + 1];
        cp0 += hv.z * w2local[4 * i4 + 2];
        cp1 += hv.w * w2local[4 * i4 + 3];
      }
      float csum = cp0 + cp1;
      csum += __shfl_xor(csum, 16);
      csum += __shfl_xor(csum, 32);
      Uk = __builtin_amdgcn_exp2f(csum * C2);
    }
    // D: wave w, k in [16w,+16); lane owns t in {lane,64+,128+,192+}
    {
      float uL[16];
      #pragma unroll
      for (int i = 0; i < 16; ++i) uL[i] = rdlane(Uk, i);
      #pragma unroll
      for (int tt = 0; tt < 4; ++tt) {
        const float* Er = &E[(64 * tt + lane) * EST + 16 * w];
        float4 e0 = *(const float4*)(Er + 0);
        float4 e1 = *(const float4*)(Er + 4);
        float4 e2 = *(const float4*)(Er + 8);
        float4 e3 = *(const float4*)(Er + 12);
        float a0 = 0.0f, a1 = 0.0f;
        float t0, t1, n;
        t0 = fmaf(e0.x, uL[ 0], 1.0f); t1 = fmaf(e0.y, uL[ 1], 1.0f);
        n  = fmaf(vL[ 1], t0, vL[ 0] * t1);
        a0 = fmaf(n, __builtin_amdgcn_rcpf(t0 * t1), a0);
        t0 = fmaf(e0.z, uL[ 2], 1.0f); t1 = fmaf(e0.w, uL[ 3], 1.0f);
        n  = fmaf(vL[ 3], t0, vL[ 2] * t1);
        a1 = fmaf(n, __builtin_amdgcn_rcpf(t0 * t1), a1);
        t0 = fmaf(e1.x, uL[ 4], 1.0f); t1 = fmaf(e1.y, uL[ 5], 1.0f);
        n  = fmaf(vL[ 5], t0, vL[ 4] * t1);
        a0 = fmaf(n, __builtin_amdgcn_rcpf(t0 * t1), a0);
        t0 = fmaf(e1.z, uL[ 6], 1.0f); t1 = fmaf(e1.w, uL[ 7], 1.0f);
        n  = fmaf(vL[ 7], t0, vL[ 6] * t1);
        a1 = fmaf(n, __builtin_amdgcn_rcpf(t0 * t1), a1);
        t0 = fmaf(e2.x, uL[ 8], 1.0f); t1 = fmaf(e2.y, uL[ 9], 1.0f);
        n  = fmaf(vL[ 9], t0, vL[ 8] * t1);
        a0 = fmaf(n, __builtin_amdgcn_rcpf(t0 * t1), a0);
        t0 = fmaf(e2.z, uL[10], 1.0f); t1 = fmaf(e2.w, uL[11], 1.0f);
        n  = fmaf(vL[11], t0, vL[10] * t1);
        a1 = fmaf(n, __builtin_amdgcn_rcpf(t0 * t1), a1);
        t0 = fmaf(e3.x, uL[12], 1.0f); t1 = fmaf(e3.y, uL[13], 1.0f);
        n  = fmaf(vL[13], t0, vL[12] * t1);
        a0 = fmaf(n, __builtin_amdgcn_rcpf(t0 * t1), a0);
        t0 = fmaf(e3.z, uL[14], 1.0f); t1 = fmaf(e3.w, uL[15], 1.0f);
        n  = fmaf(vL[15], t0, vL[14] * t1);
        a1 = fmaf(n, __builtin_amdgcn_rcpf(t0 * t1), a1);
        scp[w * SCPS + 64 * tt + lane] = a0 + a1;
      }
    }
    // Apre: zpart = h_step @ Wr; h via broadcast b128 reads (kq wave-uniform)
    {
      const float4* h4 = (const float4*)(hbuf + 32 * kq);
      float4 zac = {0.f, 0.f, 0.f, 0.f};
      #pragma unroll
      for (int i4 = 0; i4 < 8; ++i4) {
        float4 hv = h4[i4];
        zac.x += hv.x * wr4[4 * i4 + 0].x;
        zac.y += hv.x * wr4[4 * i4 + 0].y;
        zac.z += hv.x * wr4[4 * i4 + 0].z;
        zac.w += hv.x * wr4[4 * i4 + 0].w;
        zac.x += hv.y * wr4[4 * i4 + 1].x;
        zac.y += hv.y * wr4[4 * i4 + 1].y;
        zac.z += hv.y * wr4[4 * i4 + 1].z;
        zac.w += hv.y * wr4[4 * i4 + 1].w;
        zac.x += hv.z * wr4[4 * i4 + 2].x;
        zac.y += hv.z * wr4[4 * i4 + 2].y;
        zac.z += hv.z * wr4[4 * i4 + 2].z;
        zac.w += hv.z * wr4[4 * i4 + 2].w;
        zac.x += hv.w * wr4[4 * i4 + 3].x;
        zac.y += hv.w * wr4[4 * i4 + 3].y;
        zac.z += hv.w * wr4[4 * i4 + 3].z;
        zac.w += hv.w * wr4[4 * i4 + 3].w;
      }
      *(float4*)(&zpart[kq * 512 + 4 * cs]) = zac;
    }
    __syncthreads();                 // (W3) scp + zpart visible
  }

  // ---------------- peel: reduce + store final row (step 255) ----------------
  if (w >= 4) {
    float4 sc = {0.f, 0.f, 0.f, 0.f};
    #pragma unroll
    for (int q = 0; q < 8; ++q) {
      float4 v = *(const float4*)(&scp[q * SCPS + 4 * lane]);
      sc.x += v.x; sc.y += v.y; sc.z += v.z; sc.w += v.w;
    }
    sc.x += svr; sc.y += svr; sc.z += svr; sc.w += svr;
    float p0 = __builtin_amdgcn_exp2f((sc.x - 12.0f) * L2E);
    float p1 = __builtin_amdgcn_exp2f((sc.y - 12.0f) * L2E);
    float p2 = __builtin_amdgcn_exp2f((sc.z - 12.0f) * L2E);
    float p3 = __builtin_amdgcn_exp2f((sc.w - 12.0f) * L2E);
    float ws4 = (p0 + p1) + (p2 + p3);
    #pragma unroll
    for (int o = 1; o < 64; o <<= 1) ws4 += __shfl_xor(ws4, o);
    if ((lane >> 4) == (w - 4)) {
      float rs = __builtin_amdgcn_rcpf(ws4);
      float4 po = {p0 * rs, p1 * rs, p2 * rs, p3 * rs};
      *(float4*)(&outb[(size_t)255 * TT + 4 * lane]) = po;
    }
  }
}

extern "C" void kernel_launch(void* const* d_in, const int* in_sizes, int n_in,
                              void* d_out, int out_size, void* d_ws, size_t ws_size,
                              hipStream_t stream) {
  (void)in_sizes; (void)n_in; (void)d_ws; (void)ws_size; (void)out_size;
  const float* x    = (const float*)d_in[0];
  const float* enc  = (const float*)d_in[1];
  const float* h0   = (const float*)d_in[2];
  const float* c0   = (const float*)d_in[3];
  const float* W1   = (const float*)d_in[4];
  const float* W2   = (const float*)d_in[5];
  const float* V    = (const float*)d_in[6];
  const float* Wk   = (const float*)d_in[7];
  const float* Wr   = (const float*)d_in[8];
  const float* bias = (const float*)d_in[9];
  float* out = (float*)d_out;

  decoder_kernel<<<64, 512, 0, stream>>>(x, enc, h0, c0, W1, W2, V, Wk, Wr, bias, out);
}